// Round 1
// baseline (3119.724 us; speedup 1.0000x reference)
//
#include <hip/hip_runtime.h>

#define EMB 64

// init: A = emb, out(acc) = emb, B = 0   (all fp32, float4-vectorized)
__global__ void lgcn_init(const float4* __restrict__ emb,
                          float4* __restrict__ A,
                          float4* __restrict__ acc,
                          float4* __restrict__ B, int n4) {
    int i = blockIdx.x * blockDim.x + threadIdx.x;
    if (i < n4) {
        float4 v = emb[i];
        A[i]   = v;
        acc[i] = v;
        B[i]   = make_float4(0.f, 0.f, 0.f, 0.f);
    }
}

// One wave (64 lanes) per edge; lane d handles embedding dim d.
// Gather x[col[e]] is one coalesced 256B read per wave; scatter-add to
// y[row[e]] is 64 contiguous atomics (coalesce at L2).
__global__ void lgcn_spmm(const int* __restrict__ row,
                          const int* __restrict__ col,
                          const float* __restrict__ val,
                          const float* __restrict__ x,
                          float* __restrict__ y, int E) {
    int gid = blockIdx.x * blockDim.x + threadIdx.x;
    int e = gid >> 6;            // 4 edges per 256-thread block
    if (e >= E) return;
    int d = threadIdx.x & 63;
    int r = row[e];
    int c = col[e];
    float v = val[e];
    atomicAdd(y + (size_t)r * EMB + d, v * x[(size_t)c * EMB + d]);
}

// acc += X; Y = 0   (fused: accumulate just-produced layer, zero next target)
__global__ void lgcn_addzero(float4* __restrict__ acc,
                             const float4* __restrict__ X,
                             float4* __restrict__ Y, int n4) {
    int i = blockIdx.x * blockDim.x + threadIdx.x;
    if (i < n4) {
        float4 a = acc[i];
        float4 xv = X[i];
        a.x += xv.x; a.y += xv.y; a.z += xv.z; a.w += xv.w;
        acc[i] = a;
        Y[i] = make_float4(0.f, 0.f, 0.f, 0.f);
    }
}

// acc = (acc + X) * 0.25
__global__ void lgcn_final(float4* __restrict__ acc,
                           const float4* __restrict__ X, int n4) {
    int i = blockIdx.x * blockDim.x + threadIdx.x;
    if (i < n4) {
        float4 a = acc[i];
        float4 xv = X[i];
        a.x = (a.x + xv.x) * 0.25f;
        a.y = (a.y + xv.y) * 0.25f;
        a.z = (a.z + xv.z) * 0.25f;
        a.w = (a.w + xv.w) * 0.25f;
        acc[i] = a;
    }
}

extern "C" void kernel_launch(void* const* d_in, const int* in_sizes, int n_in,
                              void* d_out, int out_size, void* d_ws, size_t ws_size,
                              hipStream_t stream) {
    const float* emb = (const float*)d_in[0];
    const int*   row = (const int*)d_in[1];
    const int*   col = (const int*)d_in[2];
    const float* val = (const float*)d_in[3];
    float* acc = (float*)d_out;

    const int N = in_sizes[0] / EMB;   // 400000
    const int E = in_sizes[1];         // 4000000

    float* A = (float*)d_ws;                       // x_curr
    float* B = A + (size_t)N * EMB;                // x_next

    const int n4 = N * EMB / 4;
    const int TB = 256;
    const int ew_blocks = (n4 + TB - 1) / TB;
    const int spmm_blocks = (E + 3) / 4;           // 4 edges (waves) per block

    // acc = emb, A = emb, B = 0
    lgcn_init<<<ew_blocks, TB, 0, stream>>>((const float4*)emb, (float4*)A,
                                            (float4*)acc, (float4*)B, n4);
    // layer 1: B = spmm(A); acc += B; A = 0
    lgcn_spmm<<<spmm_blocks, TB, 0, stream>>>(row, col, val, A, B, E);
    lgcn_addzero<<<ew_blocks, TB, 0, stream>>>((float4*)acc, (const float4*)B,
                                               (float4*)A, n4);
    // layer 2: A = spmm(B); acc += A; B = 0
    lgcn_spmm<<<spmm_blocks, TB, 0, stream>>>(row, col, val, B, A, E);
    lgcn_addzero<<<ew_blocks, TB, 0, stream>>>((float4*)acc, (const float4*)A,
                                               (float4*)B, n4);
    // layer 3: B = spmm(A); acc = (acc + B) / 4
    lgcn_spmm<<<spmm_blocks, TB, 0, stream>>>(row, col, val, A, B, E);
    lgcn_final<<<ew_blocks, TB, 0, stream>>>((float4*)acc, (const float4*)B, n4);
}

// Round 2
// 1844.980 us; speedup vs baseline: 1.6909x; 1.6909x over previous
//
#include <hip/hip_runtime.h>

#define EMB 64
#define SCAN_B 256

// ---------------- CSR build ----------------

__global__ void zero_ints(int* __restrict__ p, int n) {
    int i = blockIdx.x * blockDim.x + threadIdx.x;
    if (i < n) p[i] = 0;
}

__global__ void hist_rows(const int* __restrict__ row, int* __restrict__ S, int E) {
    int e = blockIdx.x * blockDim.x + threadIdx.x;
    if (e < E) atomicAdd(&S[row[e]], 1);
}

// per-block sums of S
__global__ void scan_block_sums(const int* __restrict__ S, int* __restrict__ bsum, int N) {
    __shared__ int sdata[SCAN_B];
    int i = blockIdx.x * SCAN_B + threadIdx.x;
    sdata[threadIdx.x] = (i < N) ? S[i] : 0;
    __syncthreads();
    for (int off = SCAN_B / 2; off > 0; off >>= 1) {
        if (threadIdx.x < off) sdata[threadIdx.x] += sdata[threadIdx.x + off];
        __syncthreads();
    }
    if (threadIdx.x == 0) bsum[blockIdx.x] = sdata[0];
}

// exclusive scan of bsum in place (single block, 1024 threads, 2 elems/thread)
__global__ void scan_sums(int* __restrict__ bsum, int nb) {
    __shared__ int part[1024];
    int t = threadIdx.x;
    int i0 = 2 * t, i1 = 2 * t + 1;
    int a = (i0 < nb) ? bsum[i0] : 0;
    int b = (i1 < nb) ? bsum[i1] : 0;
    part[t] = a + b;
    __syncthreads();
    for (int off = 1; off < 1024; off <<= 1) {
        int v = part[t];
        int add = (t >= off) ? part[t - off] : 0;
        __syncthreads();
        part[t] = v + add;
        __syncthreads();
    }
    int excl = (t == 0) ? 0 : part[t - 1];
    if (i0 < nb) bsum[i0] = excl;
    if (i1 < nb) bsum[i1] = excl + a;
}

// S[i] = exclusive_scan(S)[i] + bsum[block]  (in place)
__global__ void scan_apply(int* __restrict__ S, const int* __restrict__ bsum, int N) {
    __shared__ int sdata[SCAN_B];
    int i = blockIdx.x * SCAN_B + threadIdx.x;
    int v = (i < N) ? S[i] : 0;
    sdata[threadIdx.x] = v;
    __syncthreads();
    for (int off = 1; off < SCAN_B; off <<= 1) {
        int val = sdata[threadIdx.x];
        int add = (threadIdx.x >= off) ? sdata[threadIdx.x - off] : 0;
        __syncthreads();
        sdata[threadIdx.x] = val + add;
        __syncthreads();
    }
    int excl = (threadIdx.x == 0 ? 0 : sdata[threadIdx.x - 1]) + bsum[blockIdx.x];
    if (i < N) S[i] = excl;
}

// scatter edges into row-sorted order; S (holding start[r]) is destructively
// advanced by the atomic cursors, ending as end[r] == start[r+1].
__global__ void scatter_edges(const int* __restrict__ row, const int* __restrict__ col,
                              const float* __restrict__ val,
                              int* __restrict__ S, uint2* __restrict__ epack, int E) {
    int e = blockIdx.x * blockDim.x + threadIdx.x;
    if (e >= E) return;
    int r = row[e];
    int pos = atomicAdd(&S[r], 1);
    epack[pos] = make_uint2((unsigned)col[e], __float_as_uint(val[e]));
}

// ---------------- SpMM (one wave per row, no atomics) ----------------
// After scatter, S[r] == end of row r; start of row r == S[r-1] (0 for r==0).
// mode 0: y = s; acc = emb + s        (layer 1, fuses acc init)
// mode 1: y = s; acc += s             (layer 2)
// mode 2: acc = (acc + s) * 0.25      (layer 3, no y write)
__global__ void spmm_csr(const uint2* __restrict__ epack, const int* __restrict__ S,
                         const float* __restrict__ x, const float* __restrict__ emb,
                         float* __restrict__ y, float* __restrict__ acc,
                         int N, int mode) {
    int gid = blockIdx.x * blockDim.x + threadIdx.x;
    int r = gid >> 6;
    if (r >= N) return;
    int d = threadIdx.x & 63;
    int beg = (r == 0) ? 0 : S[r - 1];
    int end = S[r];
    float s = 0.f;
    if (beg < end) {
        uint2 p = epack[beg];                    // prefetch first edge
        for (int k = beg; k < end; ++k) {
            uint2 pn = (k + 1 < end) ? epack[k + 1] : p;   // prefetch next edge
            s += __uint_as_float(p.y) * x[(size_t)p.x * EMB + d];
            p = pn;
        }
    }
    size_t o = (size_t)r * EMB + d;
    if (mode == 0)      { y[o] = s; acc[o] = emb[o] + s; }
    else if (mode == 1) { y[o] = s; acc[o] += s; }
    else                { acc[o] = (acc[o] + s) * 0.25f; }
}

// ---------------- fallback path (round-1 atomic version) ----------------

__global__ void lgcn_init(const float4* __restrict__ emb, float4* __restrict__ A,
                          float4* __restrict__ acc, float4* __restrict__ B, int n4) {
    int i = blockIdx.x * blockDim.x + threadIdx.x;
    if (i < n4) { float4 v = emb[i]; A[i] = v; acc[i] = v; B[i] = make_float4(0,0,0,0); }
}
__global__ void lgcn_spmm(const int* __restrict__ row, const int* __restrict__ col,
                          const float* __restrict__ val, const float* __restrict__ x,
                          float* __restrict__ y, int E) {
    int gid = blockIdx.x * blockDim.x + threadIdx.x;
    int e = gid >> 6;
    if (e >= E) return;
    int d = threadIdx.x & 63;
    atomicAdd(y + (size_t)row[e] * EMB + d, val[e] * x[(size_t)col[e] * EMB + d]);
}
__global__ void lgcn_addzero(float4* __restrict__ acc, const float4* __restrict__ X,
                             float4* __restrict__ Y, int n4) {
    int i = blockIdx.x * blockDim.x + threadIdx.x;
    if (i < n4) {
        float4 a = acc[i]; float4 xv = X[i];
        a.x += xv.x; a.y += xv.y; a.z += xv.z; a.w += xv.w;
        acc[i] = a; Y[i] = make_float4(0,0,0,0);
    }
}
__global__ void lgcn_final(float4* __restrict__ acc, const float4* __restrict__ X, int n4) {
    int i = blockIdx.x * blockDim.x + threadIdx.x;
    if (i < n4) {
        float4 a = acc[i]; float4 xv = X[i];
        a.x = (a.x + xv.x) * 0.25f; a.y = (a.y + xv.y) * 0.25f;
        a.z = (a.z + xv.z) * 0.25f; a.w = (a.w + xv.w) * 0.25f;
        acc[i] = a;
    }
}

extern "C" void kernel_launch(void* const* d_in, const int* in_sizes, int n_in,
                              void* d_out, int out_size, void* d_ws, size_t ws_size,
                              hipStream_t stream) {
    const float* emb = (const float*)d_in[0];
    const int*   row = (const int*)d_in[1];
    const int*   col = (const int*)d_in[2];
    const float* val = (const float*)d_in[3];
    float* acc = (float*)d_out;

    const int N = in_sizes[0] / EMB;   // 400000
    const int E = in_sizes[1];         // 4000000
    const int TB = 256;

    const size_t buf_elems = (size_t)N * EMB;
    const int nb = (N + SCAN_B - 1) / SCAN_B;

    // ws layout (CSR path): A | B | epack[E] | S[N] | bsum[nb]
    const size_t need = buf_elems * 4 * 2 + (size_t)E * 8 + (size_t)N * 4 + (size_t)nb * 4;

    float* A = (float*)d_ws;
    float* B = A + buf_elems;

    if (ws_size >= need) {
        uint2* epack = (uint2*)(B + buf_elems);
        int*   S     = (int*)(epack + E);
        int*   bsum  = S + N;

        const int eb  = (E + TB - 1) / TB;
        const int nbN = (N + TB - 1) / TB;
        const int spmm_blocks = (N + 3) / 4;   // 4 rows (waves) per 256-thread block

        // ---- build CSR (once, reused by all 3 layers) ----
        zero_ints<<<nbN, TB, 0, stream>>>(S, N);
        hist_rows<<<eb, TB, 0, stream>>>(row, S, E);
        scan_block_sums<<<nb, SCAN_B, 0, stream>>>(S, bsum, N);
        scan_sums<<<1, 1024, 0, stream>>>(bsum, nb);
        scan_apply<<<nb, SCAN_B, 0, stream>>>(S, bsum, N);
        scatter_edges<<<eb, TB, 0, stream>>>(row, col, val, S, epack, E);

        // ---- 3 fused SpMM layers ----
        // layer 1: B = A@emb ; acc = emb + B
        spmm_csr<<<spmm_blocks, TB, 0, stream>>>(epack, S, emb, emb, B, acc, N, 0);
        // layer 2: A = A@B ; acc += A
        spmm_csr<<<spmm_blocks, TB, 0, stream>>>(epack, S, B, nullptr, A, acc, N, 1);
        // layer 3: acc = (acc + A@A_buf) * 0.25
        spmm_csr<<<spmm_blocks, TB, 0, stream>>>(epack, S, A, nullptr, nullptr, acc, N, 2);
    } else {
        // fallback: round-1 atomic path (needs only 2 ping-pong buffers)
        const int n4 = (int)(buf_elems / 4);
        const int ew_blocks = (n4 + TB - 1) / TB;
        const int spmm_blocks = (E + 3) / 4;
        lgcn_init<<<ew_blocks, TB, 0, stream>>>((const float4*)emb, (float4*)A,
                                                (float4*)acc, (float4*)B, n4);
        lgcn_spmm<<<spmm_blocks, TB, 0, stream>>>(row, col, val, A, B, E);
        lgcn_addzero<<<ew_blocks, TB, 0, stream>>>((float4*)acc, (const float4*)B,
                                                   (float4*)A, n4);
        lgcn_spmm<<<spmm_blocks, TB, 0, stream>>>(row, col, val, B, A, E);
        lgcn_addzero<<<ew_blocks, TB, 0, stream>>>((float4*)acc, (const float4*)A,
                                                   (float4*)B, n4);
        lgcn_spmm<<<spmm_blocks, TB, 0, stream>>>(row, col, val, A, B, E);
        lgcn_final<<<ew_blocks, TB, 0, stream>>>((float4*)acc, (const float4*)B, n4);
    }
}

// Round 3
// 1446.058 us; speedup vs baseline: 2.1574x; 1.2759x over previous
//
#include <hip/hip_runtime.h>

#define EMB 64
#define SCAN_B 256

// ---------------- CSR build ----------------

__global__ void zero_ints(int* __restrict__ p, int n) {
    int i = blockIdx.x * blockDim.x + threadIdx.x;
    if (i < n) p[i] = 0;
}

__global__ void hist_rows(const int* __restrict__ row, int* __restrict__ S, int E) {
    int e = blockIdx.x * blockDim.x + threadIdx.x;
    if (e < E) atomicAdd(&S[row[e]], 1);
}

__global__ void scan_block_sums(const int* __restrict__ S, int* __restrict__ bsum, int N) {
    __shared__ int sdata[SCAN_B];
    int i = blockIdx.x * SCAN_B + threadIdx.x;
    sdata[threadIdx.x] = (i < N) ? S[i] : 0;
    __syncthreads();
    for (int off = SCAN_B / 2; off > 0; off >>= 1) {
        if (threadIdx.x < off) sdata[threadIdx.x] += sdata[threadIdx.x + off];
        __syncthreads();
    }
    if (threadIdx.x == 0) bsum[blockIdx.x] = sdata[0];
}

__global__ void scan_sums(int* __restrict__ bsum, int nb) {
    __shared__ int part[1024];
    int t = threadIdx.x;
    int i0 = 2 * t, i1 = 2 * t + 1;
    int a = (i0 < nb) ? bsum[i0] : 0;
    int b = (i1 < nb) ? bsum[i1] : 0;
    part[t] = a + b;
    __syncthreads();
    for (int off = 1; off < 1024; off <<= 1) {
        int v = part[t];
        int add = (t >= off) ? part[t - off] : 0;
        __syncthreads();
        part[t] = v + add;
        __syncthreads();
    }
    int excl = (t == 0) ? 0 : part[t - 1];
    if (i0 < nb) bsum[i0] = excl;
    if (i1 < nb) bsum[i1] = excl + a;
}

__global__ void scan_apply(int* __restrict__ S, const int* __restrict__ bsum, int N) {
    __shared__ int sdata[SCAN_B];
    int i = blockIdx.x * SCAN_B + threadIdx.x;
    int v = (i < N) ? S[i] : 0;
    sdata[threadIdx.x] = v;
    __syncthreads();
    for (int off = 1; off < SCAN_B; off <<= 1) {
        int val = sdata[threadIdx.x];
        int add = (threadIdx.x >= off) ? sdata[threadIdx.x - off] : 0;
        __syncthreads();
        sdata[threadIdx.x] = val + add;
        __syncthreads();
    }
    int excl = (threadIdx.x == 0 ? 0 : sdata[threadIdx.x - 1]) + bsum[blockIdx.x];
    if (i < N) S[i] = excl;
}

__global__ void scatter_edges(const int* __restrict__ row, const int* __restrict__ col,
                              const float* __restrict__ val,
                              int* __restrict__ S, uint2* __restrict__ epack, int E) {
    int e = blockIdx.x * blockDim.x + threadIdx.x;
    if (e >= E) return;
    int r = row[e];
    int pos = atomicAdd(&S[r], 1);
    epack[pos] = make_uint2((unsigned)col[e], __float_as_uint(val[e]));
}

// ---------------- SpMM: 1 wave/row, 16 edges in flight/iter ----------------
// Lanes: grp = lane>>4 (edge slot 0..3), d4 = lane&15 (float4 chunk of 64 dims).
// Per iteration the wave covers 16 edges: slot j edge = base + j*4 + grp.
// All 4 epack loads then all 4 float4-gathers are issued before any fmac,
// giving 4 KB in flight per wave (vs 256 B in round 2).
// mode 0: y = s; acc = emb + s   | mode 1: y = s; acc += s | mode 2: acc=(acc+s)*0.25
__global__ void spmm_csr(const uint2* __restrict__ epack, const int* __restrict__ S,
                         const float* __restrict__ x, const float* __restrict__ emb,
                         float* __restrict__ y, float* __restrict__ acc,
                         int N, int mode) {
    int r = (blockIdx.x * blockDim.x + threadIdx.x) >> 6;
    if (r >= N) return;
    int lane = threadIdx.x & 63;
    int grp = lane >> 4;
    int d4  = lane & 15;

    int beg = (r == 0) ? 0 : S[r - 1];
    int end = S[r];

    float4 s = make_float4(0.f, 0.f, 0.f, 0.f);
    const float4 z4 = make_float4(0.f, 0.f, 0.f, 0.f);

    for (int base = beg; base < end; base += 16) {
        uint2 p0 = make_uint2(0u,0u), p1 = p0, p2 = p0, p3 = p0;
        int i0 = base + grp, i1 = i0 + 4, i2 = i0 + 8, i3 = i0 + 12;
        if (i0 < end) p0 = epack[i0];
        if (i1 < end) p1 = epack[i1];
        if (i2 < end) p2 = epack[i2];
        if (i3 < end) p3 = epack[i3];
        // issue all gathers before any consume
        float4 x0 = (i0 < end) ? ((const float4*)(x + (size_t)p0.x * EMB))[d4] : z4;
        float4 x1 = (i1 < end) ? ((const float4*)(x + (size_t)p1.x * EMB))[d4] : z4;
        float4 x2 = (i2 < end) ? ((const float4*)(x + (size_t)p2.x * EMB))[d4] : z4;
        float4 x3 = (i3 < end) ? ((const float4*)(x + (size_t)p3.x * EMB))[d4] : z4;
        float w0 = (i0 < end) ? __uint_as_float(p0.y) : 0.f;
        float w1 = (i1 < end) ? __uint_as_float(p1.y) : 0.f;
        float w2 = (i2 < end) ? __uint_as_float(p2.y) : 0.f;
        float w3 = (i3 < end) ? __uint_as_float(p3.y) : 0.f;
        s.x += w0*x0.x; s.y += w0*x0.y; s.z += w0*x0.z; s.w += w0*x0.w;
        s.x += w1*x1.x; s.y += w1*x1.y; s.z += w1*x1.z; s.w += w1*x1.w;
        s.x += w2*x2.x; s.y += w2*x2.y; s.z += w2*x2.z; s.w += w2*x2.w;
        s.x += w3*x3.x; s.y += w3*x3.y; s.z += w3*x3.z; s.w += w3*x3.w;
    }

    // reduce the 4 edge-slot partials (lanes sharing d4)
    s.x += __shfl_xor(s.x, 32); s.y += __shfl_xor(s.y, 32);
    s.z += __shfl_xor(s.z, 32); s.w += __shfl_xor(s.w, 32);
    s.x += __shfl_xor(s.x, 16); s.y += __shfl_xor(s.y, 16);
    s.z += __shfl_xor(s.z, 16); s.w += __shfl_xor(s.w, 16);

    if (lane < 16) {
        size_t o4 = (size_t)r * 16 + d4;      // float4 index
        if (mode == 0) {
            float4 e4 = ((const float4*)emb)[o4];
            ((float4*)y)[o4] = s;
            ((float4*)acc)[o4] = make_float4(e4.x+s.x, e4.y+s.y, e4.z+s.z, e4.w+s.w);
        } else if (mode == 1) {
            float4 a4 = ((float4*)acc)[o4];
            ((float4*)y)[o4] = s;
            ((float4*)acc)[o4] = make_float4(a4.x+s.x, a4.y+s.y, a4.z+s.z, a4.w+s.w);
        } else {
            float4 a4 = ((float4*)acc)[o4];
            ((float4*)acc)[o4] = make_float4((a4.x+s.x)*0.25f, (a4.y+s.y)*0.25f,
                                             (a4.z+s.z)*0.25f, (a4.w+s.w)*0.25f);
        }
    }
}

// ---------------- fallback path (round-1 atomic version) ----------------

__global__ void lgcn_init(const float4* __restrict__ emb, float4* __restrict__ A,
                          float4* __restrict__ acc, float4* __restrict__ B, int n4) {
    int i = blockIdx.x * blockDim.x + threadIdx.x;
    if (i < n4) { float4 v = emb[i]; A[i] = v; acc[i] = v; B[i] = make_float4(0,0,0,0); }
}
__global__ void lgcn_spmm(const int* __restrict__ row, const int* __restrict__ col,
                          const float* __restrict__ val, const float* __restrict__ x,
                          float* __restrict__ y, int E) {
    int gid = blockIdx.x * blockDim.x + threadIdx.x;
    int e = gid >> 6;
    if (e >= E) return;
    int d = threadIdx.x & 63;
    atomicAdd(y + (size_t)row[e] * EMB + d, val[e] * x[(size_t)col[e] * EMB + d]);
}
__global__ void lgcn_addzero(float4* __restrict__ acc, const float4* __restrict__ X,
                             float4* __restrict__ Y, int n4) {
    int i = blockIdx.x * blockDim.x + threadIdx.x;
    if (i < n4) {
        float4 a = acc[i]; float4 xv = X[i];
        a.x += xv.x; a.y += xv.y; a.z += xv.z; a.w += xv.w;
        acc[i] = a; Y[i] = make_float4(0,0,0,0);
    }
}
__global__ void lgcn_final(float4* __restrict__ acc, const float4* __restrict__ X, int n4) {
    int i = blockIdx.x * blockDim.x + threadIdx.x;
    if (i < n4) {
        float4 a = acc[i]; float4 xv = X[i];
        a.x = (a.x + xv.x) * 0.25f; a.y = (a.y + xv.y) * 0.25f;
        a.z = (a.z + xv.z) * 0.25f; a.w = (a.w + xv.w) * 0.25f;
        acc[i] = a;
    }
}

extern "C" void kernel_launch(void* const* d_in, const int* in_sizes, int n_in,
                              void* d_out, int out_size, void* d_ws, size_t ws_size,
                              hipStream_t stream) {
    const float* emb = (const float*)d_in[0];
    const int*   row = (const int*)d_in[1];
    const int*   col = (const int*)d_in[2];
    const float* val = (const float*)d_in[3];
    float* acc = (float*)d_out;

    const int N = in_sizes[0] / EMB;   // 400000
    const int E = in_sizes[1];         // 4000000
    const int TB = 256;

    const size_t buf_elems = (size_t)N * EMB;
    const int nb = (N + SCAN_B - 1) / SCAN_B;

    const size_t need = buf_elems * 4 * 2 + (size_t)E * 8 + (size_t)N * 4 + (size_t)nb * 4;

    float* A = (float*)d_ws;
    float* B = A + buf_elems;

    if (ws_size >= need) {
        uint2* epack = (uint2*)(B + buf_elems);
        int*   S     = (int*)(epack + E);
        int*   bsum  = S + N;

        const int eb  = (E + TB - 1) / TB;
        const int nbN = (N + TB - 1) / TB;
        const int spmm_blocks = (N + 3) / 4;   // 4 rows (waves) per 256-thread block

        zero_ints<<<nbN, TB, 0, stream>>>(S, N);
        hist_rows<<<eb, TB, 0, stream>>>(row, S, E);
        scan_block_sums<<<nb, SCAN_B, 0, stream>>>(S, bsum, N);
        scan_sums<<<1, 1024, 0, stream>>>(bsum, nb);
        scan_apply<<<nb, SCAN_B, 0, stream>>>(S, bsum, N);
        scatter_edges<<<eb, TB, 0, stream>>>(row, col, val, S, epack, E);

        spmm_csr<<<spmm_blocks, TB, 0, stream>>>(epack, S, emb, emb, B, acc, N, 0);
        spmm_csr<<<spmm_blocks, TB, 0, stream>>>(epack, S, B, nullptr, A, acc, N, 1);
        spmm_csr<<<spmm_blocks, TB, 0, stream>>>(epack, S, A, nullptr, nullptr, acc, N, 2);
    } else {
        const int n4 = (int)(buf_elems / 4);
        const int ew_blocks = (n4 + TB - 1) / TB;
        const int spmm_blocks = (E + 3) / 4;
        lgcn_init<<<ew_blocks, TB, 0, stream>>>((const float4*)emb, (float4*)A,
                                                (float4*)acc, (float4*)B, n4);
        lgcn_spmm<<<spmm_blocks, TB, 0, stream>>>(row, col, val, A, B, E);
        lgcn_addzero<<<ew_blocks, TB, 0, stream>>>((float4*)acc, (const float4*)B,
                                                   (float4*)A, n4);
        lgcn_spmm<<<spmm_blocks, TB, 0, stream>>>(row, col, val, B, A, E);
        lgcn_addzero<<<ew_blocks, TB, 0, stream>>>((float4*)acc, (const float4*)A,
                                                   (float4*)B, n4);
        lgcn_spmm<<<spmm_blocks, TB, 0, stream>>>(row, col, val, A, B, E);
        lgcn_final<<<ew_blocks, TB, 0, stream>>>((float4*)acc, (const float4*)B, n4);
    }
}

// Round 4
// 1162.130 us; speedup vs baseline: 2.6845x; 1.2443x over previous
//
#include <hip/hip_runtime.h>

#define EMB 64
#define SCAN_B 256

// ---- bf16 helpers (manual, RNE) ----
__device__ inline unsigned short f2bf(float f) {
    unsigned u = __float_as_uint(f);
    return (unsigned short)((u + 0x7fffu + ((u >> 16) & 1u)) >> 16);
}
__device__ inline float bl(unsigned u) { return __uint_as_float(u << 16); }       // low bf16
__device__ inline float bh(unsigned u) { return __uint_as_float(u & 0xffff0000u); } // high bf16

// ---------------- CSR build ----------------

__global__ void zero_ints(int* __restrict__ p, int n) {
    int i = blockIdx.x * blockDim.x + threadIdx.x;
    if (i < n) p[i] = 0;
}

__global__ void hist_rows(const int* __restrict__ row, int* __restrict__ S, int E) {
    int e = blockIdx.x * blockDim.x + threadIdx.x;
    if (e < E) atomicAdd(&S[row[e]], 1);
}

__global__ void scan_block_sums(const int* __restrict__ S, int* __restrict__ bsum, int N) {
    __shared__ int sdata[SCAN_B];
    int i = blockIdx.x * SCAN_B + threadIdx.x;
    sdata[threadIdx.x] = (i < N) ? S[i] : 0;
    __syncthreads();
    for (int off = SCAN_B / 2; off > 0; off >>= 1) {
        if (threadIdx.x < off) sdata[threadIdx.x] += sdata[threadIdx.x + off];
        __syncthreads();
    }
    if (threadIdx.x == 0) bsum[blockIdx.x] = sdata[0];
}

__global__ void scan_sums(int* __restrict__ bsum, int nb) {
    __shared__ int part[1024];
    int t = threadIdx.x;
    int i0 = 2 * t, i1 = 2 * t + 1;
    int a = (i0 < nb) ? bsum[i0] : 0;
    int b = (i1 < nb) ? bsum[i1] : 0;
    part[t] = a + b;
    __syncthreads();
    for (int off = 1; off < 1024; off <<= 1) {
        int v = part[t];
        int add = (t >= off) ? part[t - off] : 0;
        __syncthreads();
        part[t] = v + add;
        __syncthreads();
    }
    int excl = (t == 0) ? 0 : part[t - 1];
    if (i0 < nb) bsum[i0] = excl;
    if (i1 < nb) bsum[i1] = excl + a;
}

__global__ void scan_apply(int* __restrict__ S, const int* __restrict__ bsum, int N) {
    __shared__ int sdata[SCAN_B];
    int i = blockIdx.x * SCAN_B + threadIdx.x;
    int v = (i < N) ? S[i] : 0;
    sdata[threadIdx.x] = v;
    __syncthreads();
    for (int off = 1; off < SCAN_B; off <<= 1) {
        int val = sdata[threadIdx.x];
        int add = (threadIdx.x >= off) ? sdata[threadIdx.x - off] : 0;
        __syncthreads();
        sdata[threadIdx.x] = val + add;
        __syncthreads();
    }
    int excl = (threadIdx.x == 0 ? 0 : sdata[threadIdx.x - 1]) + bsum[blockIdx.x];
    if (i < N) S[i] = excl;
}

// Ranged scatter: each edge chunk is visited by 8 blocks; block b only commits
// rows in range b%8. On MI355X's round-robin dispatch, b%8 == XCD id, so each
// epack window is written by one XCD -> full-line local L2 accumulation instead
// of cross-XCD partial-line ping-pong. Correct under ANY dispatch mapping.
__global__ void scatter_edges_ranged(const int* __restrict__ row, const int* __restrict__ col,
                                     const float* __restrict__ val,
                                     int* __restrict__ S, uint2* __restrict__ epack,
                                     int E, int rstep) {
    int pass  = blockIdx.x & 7;
    int chunk = blockIdx.x >> 3;
    int e = chunk * blockDim.x + threadIdx.x;
    if (e >= E) return;
    int r = row[e];
    int lo = pass * rstep;
    if (r < lo || r >= lo + rstep) return;
    int pos = atomicAdd(&S[r], 1);
    epack[pos] = make_uint2((unsigned)col[e], __float_as_uint(val[e]));
}

// emb (fp32) -> bf16 copy for layer-1 gathers
__global__ void conv_bf16(const float4* __restrict__ src, uint2* __restrict__ dst, int n4) {
    int i = blockIdx.x * blockDim.x + threadIdx.x;
    if (i < n4) {
        float4 v = src[i];
        unsigned w0 = (unsigned)f2bf(v.x) | ((unsigned)f2bf(v.y) << 16);
        unsigned w1 = (unsigned)f2bf(v.z) | ((unsigned)f2bf(v.w) << 16);
        dst[i] = make_uint2(w0, w1);
    }
}

// ---------------- SpMM: 1 wave/row, bf16 gathers (1 line/row) ----------------
// grp = lane>>4 (edge slot), d4 = lane&15 (4-dim chunk). 16 edges/iter,
// 4 independent 128B gathers in flight. Accumulate fp32, reduce via shfl_xor.
// mode 0: y=bf16(s); acc = emb + s | mode 1: y=bf16(s); acc += s | mode 2: acc=(acc+s)*0.25
__global__ void spmm_csr(const uint2* __restrict__ epack, const int* __restrict__ S,
                         const unsigned short* __restrict__ x, const float* __restrict__ emb,
                         unsigned short* __restrict__ y, float* __restrict__ acc,
                         int N, int mode) {
    int r = (blockIdx.x * blockDim.x + threadIdx.x) >> 6;
    if (r >= N) return;
    int lane = threadIdx.x & 63;
    int grp = lane >> 4;
    int d4  = lane & 15;

    int beg = (r == 0) ? 0 : S[r - 1];
    int end = S[r];

    float4 s = make_float4(0.f, 0.f, 0.f, 0.f);
    const uint2 z2 = make_uint2(0u, 0u);

    for (int base = beg; base < end; base += 16) {
        uint2 p0 = z2, p1 = z2, p2 = z2, p3 = z2;
        int i0 = base + grp, i1 = i0 + 4, i2 = i0 + 8, i3 = i0 + 12;
        if (i0 < end) p0 = epack[i0];
        if (i1 < end) p1 = epack[i1];
        if (i2 < end) p2 = epack[i2];
        if (i3 < end) p3 = epack[i3];
        // bf16 gathers: one 128B line per edge, 4 in flight before any consume
        uint2 g0 = (i0 < end) ? ((const uint2*)(x + ((size_t)p0.x << 6)))[d4] : z2;
        uint2 g1 = (i1 < end) ? ((const uint2*)(x + ((size_t)p1.x << 6)))[d4] : z2;
        uint2 g2 = (i2 < end) ? ((const uint2*)(x + ((size_t)p2.x << 6)))[d4] : z2;
        uint2 g3 = (i3 < end) ? ((const uint2*)(x + ((size_t)p3.x << 6)))[d4] : z2;
        float w0 = (i0 < end) ? __uint_as_float(p0.y) : 0.f;
        float w1 = (i1 < end) ? __uint_as_float(p1.y) : 0.f;
        float w2 = (i2 < end) ? __uint_as_float(p2.y) : 0.f;
        float w3 = (i3 < end) ? __uint_as_float(p3.y) : 0.f;
        s.x += w0 * bl(g0.x); s.y += w0 * bh(g0.x); s.z += w0 * bl(g0.y); s.w += w0 * bh(g0.y);
        s.x += w1 * bl(g1.x); s.y += w1 * bh(g1.x); s.z += w1 * bl(g1.y); s.w += w1 * bh(g1.y);
        s.x += w2 * bl(g2.x); s.y += w2 * bh(g2.x); s.z += w2 * bl(g2.y); s.w += w2 * bh(g2.y);
        s.x += w3 * bl(g3.x); s.y += w3 * bh(g3.x); s.z += w3 * bl(g3.y); s.w += w3 * bh(g3.y);
    }

    s.x += __shfl_xor(s.x, 32); s.y += __shfl_xor(s.y, 32);
    s.z += __shfl_xor(s.z, 32); s.w += __shfl_xor(s.w, 32);
    s.x += __shfl_xor(s.x, 16); s.y += __shfl_xor(s.y, 16);
    s.z += __shfl_xor(s.z, 16); s.w += __shfl_xor(s.w, 16);

    if (lane < 16) {
        size_t o4 = (size_t)r * 16 + d4;
        if (mode != 2) {
            // y (bf16, 8B/lane coalesced)
            unsigned w0 = (unsigned)f2bf(s.x) | ((unsigned)f2bf(s.y) << 16);
            unsigned w1 = (unsigned)f2bf(s.z) | ((unsigned)f2bf(s.w) << 16);
            ((uint2*)y)[o4] = make_uint2(w0, w1);
        }
        if (mode == 0) {
            float4 e4 = ((const float4*)emb)[o4];
            ((float4*)acc)[o4] = make_float4(e4.x+s.x, e4.y+s.y, e4.z+s.z, e4.w+s.w);
        } else if (mode == 1) {
            float4 a4 = ((float4*)acc)[o4];
            ((float4*)acc)[o4] = make_float4(a4.x+s.x, a4.y+s.y, a4.z+s.z, a4.w+s.w);
        } else {
            float4 a4 = ((float4*)acc)[o4];
            ((float4*)acc)[o4] = make_float4((a4.x+s.x)*0.25f, (a4.y+s.y)*0.25f,
                                             (a4.z+s.z)*0.25f, (a4.w+s.w)*0.25f);
        }
    }
}

// ---------------- fallback path (round-1 atomic version, fp32) ----------------

__global__ void lgcn_init(const float4* __restrict__ emb, float4* __restrict__ A,
                          float4* __restrict__ acc, float4* __restrict__ B, int n4) {
    int i = blockIdx.x * blockDim.x + threadIdx.x;
    if (i < n4) { float4 v = emb[i]; A[i] = v; acc[i] = v; B[i] = make_float4(0,0,0,0); }
}
__global__ void lgcn_spmm(const int* __restrict__ row, const int* __restrict__ col,
                          const float* __restrict__ val, const float* __restrict__ x,
                          float* __restrict__ y, int E) {
    int gid = blockIdx.x * blockDim.x + threadIdx.x;
    int e = gid >> 6;
    if (e >= E) return;
    int d = threadIdx.x & 63;
    atomicAdd(y + (size_t)row[e] * EMB + d, val[e] * x[(size_t)col[e] * EMB + d]);
}
__global__ void lgcn_addzero(float4* __restrict__ acc, const float4* __restrict__ X,
                             float4* __restrict__ Y, int n4) {
    int i = blockIdx.x * blockDim.x + threadIdx.x;
    if (i < n4) {
        float4 a = acc[i]; float4 xv = X[i];
        a.x += xv.x; a.y += xv.y; a.z += xv.z; a.w += xv.w;
        acc[i] = a; Y[i] = make_float4(0,0,0,0);
    }
}
__global__ void lgcn_final(float4* __restrict__ acc, const float4* __restrict__ X, int n4) {
    int i = blockIdx.x * blockDim.x + threadIdx.x;
    if (i < n4) {
        float4 a = acc[i]; float4 xv = X[i];
        a.x = (a.x + xv.x) * 0.25f; a.y = (a.y + xv.y) * 0.25f;
        a.z = (a.z + xv.z) * 0.25f; a.w = (a.w + xv.w) * 0.25f;
        acc[i] = a;
    }
}

extern "C" void kernel_launch(void* const* d_in, const int* in_sizes, int n_in,
                              void* d_out, int out_size, void* d_ws, size_t ws_size,
                              hipStream_t stream) {
    const float* emb = (const float*)d_in[0];
    const int*   row = (const int*)d_in[1];
    const int*   col = (const int*)d_in[2];
    const float* val = (const float*)d_in[3];
    float* acc = (float*)d_out;

    const int N = in_sizes[0] / EMB;   // 400000
    const int E = in_sizes[1];         // 4000000
    const int TB = 256;

    const size_t buf_elems = (size_t)N * EMB;
    const int nb = (N + SCAN_B - 1) / SCAN_B;

    // CSR ws layout: epack[E] | X0b | X1b | X2b (bf16) | S[N] | bsum[nb]
    const size_t need = (size_t)E * 8 + buf_elems * 2 * 3 + (size_t)N * 4 + (size_t)nb * 4;

    if (ws_size >= need) {
        uint2* epack = (uint2*)d_ws;
        unsigned short* X0 = (unsigned short*)(epack + E);
        unsigned short* X1 = X0 + buf_elems;
        unsigned short* X2 = X1 + buf_elems;
        int* S    = (int*)(X2 + buf_elems);
        int* bsum = S + N;

        const int eb  = (E + TB - 1) / TB;
        const int nbN = (N + TB - 1) / TB;
        const int n4  = (int)(buf_elems / 4);
        const int cvb = (n4 + TB - 1) / TB;
        const int spmm_blocks = (N + 3) / 4;
        const int rstep = (N + 7) / 8;

        // build CSR (reused by all 3 layers)
        zero_ints<<<nbN, TB, 0, stream>>>(S, N);
        hist_rows<<<eb, TB, 0, stream>>>(row, S, E);
        scan_block_sums<<<nb, SCAN_B, 0, stream>>>(S, bsum, N);
        scan_sums<<<1, 1024, 0, stream>>>(bsum, nb);
        scan_apply<<<nb, SCAN_B, 0, stream>>>(S, bsum, N);
        scatter_edges_ranged<<<eb * 8, TB, 0, stream>>>(row, col, val, S, epack, E, rstep);
        conv_bf16<<<cvb, TB, 0, stream>>>((const float4*)emb, (uint2*)X0, n4);

        // 3 fused SpMM layers (bf16 gathers, fp32 accumulate/acc)
        spmm_csr<<<spmm_blocks, TB, 0, stream>>>(epack, S, X0, emb, X1, acc, N, 0);
        spmm_csr<<<spmm_blocks, TB, 0, stream>>>(epack, S, X1, nullptr, X2, acc, N, 1);
        spmm_csr<<<spmm_blocks, TB, 0, stream>>>(epack, S, X2, nullptr, nullptr, acc, N, 2);
    } else {
        float* A = (float*)d_ws;
        float* B = A + buf_elems;
        const int n4 = (int)(buf_elems / 4);
        const int ew_blocks = (n4 + TB - 1) / TB;
        const int spmm_blocks = (E + 3) / 4;
        lgcn_init<<<ew_blocks, TB, 0, stream>>>((const float4*)emb, (float4*)A,
                                                (float4*)acc, (float4*)B, n4);
        lgcn_spmm<<<spmm_blocks, TB, 0, stream>>>(row, col, val, A, B, E);
        lgcn_addzero<<<ew_blocks, TB, 0, stream>>>((float4*)acc, (const float4*)B,
                                                   (float4*)A, n4);
        lgcn_spmm<<<spmm_blocks, TB, 0, stream>>>(row, col, val, B, A, E);
        lgcn_addzero<<<ew_blocks, TB, 0, stream>>>((float4*)acc, (const float4*)A,
                                                   (float4*)B, n4);
        lgcn_spmm<<<spmm_blocks, TB, 0, stream>>>(row, col, val, A, B, E);
        lgcn_final<<<ew_blocks, TB, 0, stream>>>((float4*)acc, (const float4*)B, n4);
    }
}